// Round 8
// baseline (3320.350 us; speedup 1.0000x reference)
//
#include <hip/hip_runtime.h>

#define B_     256
#define NI_    1152
#define NO_    10
#define DO_    16
#define DI_    8
#define PAIRS_ 160
#define NBLK_  960
#define SEGS_  96
#define ISEG_  12           // NI_/SEGS_
#define PP_    4            // pairs per wave (16 per block, 10 pair-splits)
#define SC_    4
#define NSYNC_ 11
#define MAGIC_ 0x5EAF00D

// Device-scope grid barrier. Each sync point k has its own 960-flag array in ws.
// ws is re-poisoned to 0xAA before every launch, so flags never start == MAGIC_;
// each array is written exactly once per launch (no reuse -> no ABA).
__device__ __forceinline__ void gsync(int k, int* flags)
{
    __threadfence();                       // flush this thread's writes to agent scope
    __syncthreads();                       // all block writes drained (vmcnt0)
    if (threadIdx.x == 0)
        __hip_atomic_store(&flags[k * NBLK_ + blockIdx.x], MAGIC_,
                           __ATOMIC_RELEASE, __HIP_MEMORY_SCOPE_AGENT);
    if (threadIdx.x < 64) {                // wave 0 polls all 960 flags (15/lane)
        for (int t = threadIdx.x; t < NBLK_; t += 64)
            while (__hip_atomic_load(&flags[k * NBLK_ + t],
                                     __ATOMIC_ACQUIRE, __HIP_MEMORY_SCOPE_AGENT) != MAGIC_)
                __builtin_amdgcn_s_sleep(2);
    }
    __syncthreads();                       // wave0's acquire invalidated CU caches
}

__global__ __launch_bounds__(256, 4) void caps_kernel(
    const float* __restrict__ x, const float* __restrict__ W,
    float* __restrict__ xT, float* __restrict__ blog, float* __restrict__ cmat,
    float* __restrict__ vbuf, float* __restrict__ partial, float* __restrict__ part2,
    int* __restrict__ flags, float* __restrict__ out)
{
    __shared__ __align__(16) float smem[4224];   // 16.9 KB: max(prep 4160, sv 4216, red2 1024)
    int vb   = blockIdx.x;
    int tid  = threadIdx.x;
    int lane = tid & 63;
    int wv   = __builtin_amdgcn_readfirstlane(tid >> 6);

    // ---- P0: tiled transpose x[b,d,i] -> xT[(i*8+d)*256+b]; init blog/cmat ----
    if (vb < 576) {                         // 18 i-tiles x 4 b-tiles x 8 d
        int d = vb & 7, rest = vb >> 3, tb = rest & 3, ti = rest >> 2;
        int i0 = ti * 64, b0 = tb * 64;
        float* tile = smem;                 // [64][65]
        for (int k = 0; k < 16; ++k) {
            int bL = wv * 16 + k;
            tile[bL * 65 + lane] = x[(size_t)(b0 + bL) * (NI_ * DI_) + d * NI_ + i0 + lane];
        }
        __syncthreads();
        for (int k = 0; k < 16; ++k) {
            int iL = wv * 16 + k;
            xT[((size_t)(i0 + iL) * DI_ + d) * B_ + b0 + lane] = tile[lane * 65 + iL];
        }
    } else if (vb < 576 + 45) {
        int g = (vb - 576) * 256 + tid;     // covers 11520 exactly
        if (g < NI_ * NO_) { blog[g] = 0.f; cmat[g] = 0.1f; }
    }
    gsync(0, flags);

    for (int it = 0; it < 3; ++it) {
        int base = 1 + it * 4;

        // ---- SV: block (ps=vb/96, seg=vb%96); 12 i's, 16 pairs (4/wave) ----
        {
            int seg = vb % SEGS_, ps = vb / SEGS_;
            int p0  = ps * 16 + wv * PP_;
            int b0  = lane * 4;
            int i0  = seg * ISEG_;
            float* xs0 = smem;              // 2048
            float* xs1 = smem + 2048;       // 2048
            float* cs  = smem + 4096;       // 120 (vector-loaded cmat; avoids stale K$)
            if (tid < ISEG_ * NO_) cs[tid] = cmat[i0 * NO_ + tid];

            float acc[PP_][4];
#pragma unroll
            for (int p = 0; p < PP_; ++p)
#pragma unroll
                for (int r = 0; r < 4; ++r) acc[p][r] = 0.f;

            const float4* s0 = (const float4*)(xT + (size_t)i0 * (DI_ * B_));
            float4 nx0 = s0[tid * 2], nx1 = s0[tid * 2 + 1];
            int buf = 0;
            for (int ii = 0; ii < ISEG_; ++ii) {
                float* xb = buf ? xs1 : xs0;
                ((float4*)xb)[tid * 2]     = nx0;
                ((float4*)xb)[tid * 2 + 1] = nx1;
                __syncthreads();            // one barrier per i (dbuf; R7-proven)
                if (ii + 1 < ISEG_) {
                    const float4* s2 = (const float4*)(xT + (size_t)(i0 + ii + 1) * (DI_ * B_));
                    nx0 = s2[tid * 2]; nx1 = s2[tid * 2 + 1];
                }
                float xv[DI_][4];
#pragma unroll
                for (int d = 0; d < DI_; ++d) {
                    float4 t4 = *(const float4*)&xb[d * B_ + b0];
                    xv[d][0] = t4.x; xv[d][1] = t4.y; xv[d][2] = t4.z; xv[d][3] = t4.w;
                }
                const float* wb = W + (size_t)((i0 + ii) * PAIRS_ + p0) * DI_;   // W read-only -> s_load safe
#pragma unroll
                for (int p = 0; p < PP_; ++p) {
                    const float* wr = wb + p * DI_;
                    float cv = cs[ii * NO_ + ((p0 + p) >> 4)];
#pragma unroll
                    for (int r = 0; r < 4; ++r) {
                        float u = wr[0] * xv[0][r];
                        u = fmaf(wr[1], xv[1][r], u); u = fmaf(wr[2], xv[2][r], u);
                        u = fmaf(wr[3], xv[3][r], u); u = fmaf(wr[4], xv[4][r], u);
                        u = fmaf(wr[5], xv[5][r], u); u = fmaf(wr[6], xv[6][r], u);
                        u = fmaf(wr[7], xv[7][r], u);
                        acc[p][r] = fmaf(cv, u, acc[p][r]);
                    }
                }
                buf ^= 1;
            }
#pragma unroll
            for (int p = 0; p < PP_; ++p)
                *(float4*)&partial[(size_t)(seg * PAIRS_ + p0 + p) * B_ + b0] =
                    make_float4(acc[p][0], acc[p][1], acc[p][2], acc[p][3]);
        }
        gsync(base, flags);

        // ---- RED1: 640 vblocks sum 24 segs each ----
        if (vb < PAIRS_ * SC_) {
            int pair = vb >> 2, sc = vb & 3, b = tid;
            float s = 0.f;
            for (int k = 0; k < SEGS_ / SC_; ++k)
                s += partial[(size_t)((sc * (SEGS_ / SC_) + k) * PAIRS_ + pair) * B_ + b];
            part2[((size_t)sc * PAIRS_ + pair) * B_ + b] = s;
        }
        gsync(base + 1, flags);

        // ---- RED2: 40 vblocks: finish sum, squash, vbuf (+out last iter) ----
        if (vb < NO_ * 4) {
            int j = vb >> 2, bq = vb & 3;
            int b = bq * 64 + lane;
            float* so = smem;               // 1024
#pragma unroll
            for (int oo = 0; oo < 4; ++oo) {
                int o = wv * 4 + oo, pair = j * DO_ + o;
                float s = part2[((size_t)0 * PAIRS_ + pair) * B_ + b]
                        + part2[((size_t)1 * PAIRS_ + pair) * B_ + b]
                        + part2[((size_t)2 * PAIRS_ + pair) * B_ + b]
                        + part2[((size_t)3 * PAIRS_ + pair) * B_ + b];
                so[o * 64 + lane] = s;
            }
            __syncthreads();
            float sq = 0.f;
#pragma unroll
            for (int o = 0; o < DO_; ++o) { float t = so[o * 64 + lane]; sq = fmaf(t, t, sq); }
            float f = (sq / (1.f + sq)) * rsqrtf(sq + 1e-9f);
#pragma unroll
            for (int oo = 0; oo < 4; ++oo) {
                int o = wv * 4 + oo;
                float vv = so[o * 64 + lane] * f;
                vbuf[(j * DO_ + o) * B_ + b] = vv;
                if (it == 2) out[(size_t)b * PAIRS_ + j * DO_ + o] = vv;
            }
        }
        if (it == 2) break;
        gsync(base + 2, flags);

        // ---- AGREE (+fused softmax -> cmat): 1152 i's over 960 blocks ----
        for (int i = vb; i < NI_; i += NBLK_) {
            int b0 = lane * 4;
            float* js  = smem;              // 10
            float* nbs = smem + 16;         // 10
            float xv[DI_][4];
#pragma unroll
            for (int d = 0; d < DI_; ++d) {
                float4 t4 = *(const float4*)&xT[((size_t)i * DI_ + d) * B_ + b0];
                xv[d][0] = t4.x; xv[d][1] = t4.y; xv[d][2] = t4.z; xv[d][3] = t4.w;
            }
            for (int j = wv; j < NO_; j += 4) {
                const float* wj = W + (size_t)(i * NO_ + j) * DO_ * DI_;
                float aj = 0.f;
#pragma unroll
                for (int o = 0; o < DO_; ++o) {
                    const float* wr = wj + o * DI_;                              // s_load (W ro)
                    float4 vv4 = *(const float4*)&vbuf[(j * DO_ + o) * B_ + b0]; // vector
                    float u0 = wr[0] * xv[0][0]; float u1 = wr[0] * xv[0][1];
                    float u2 = wr[0] * xv[0][2]; float u3 = wr[0] * xv[0][3];
#pragma unroll
                    for (int d = 1; d < DI_; ++d) {
                        u0 = fmaf(wr[d], xv[d][0], u0); u1 = fmaf(wr[d], xv[d][1], u1);
                        u2 = fmaf(wr[d], xv[d][2], u2); u3 = fmaf(wr[d], xv[d][3], u3);
                    }
                    aj = fmaf(u0, vv4.x, aj); aj = fmaf(u1, vv4.y, aj);
                    aj = fmaf(u2, vv4.z, aj); aj = fmaf(u3, vv4.w, aj);
                }
                for (int off = 32; off > 0; off >>= 1) aj += __shfl_down(aj, off);
                if (lane == 0) js[j] = aj;
            }
            __syncthreads();
            if (tid < NO_) {
                float nb = blog[i * NO_ + tid] + js[tid] * (1.f / B_);
                blog[i * NO_ + tid] = nb;
                nbs[tid] = nb;
            }
            __syncthreads();
            if (tid < NO_) {
                float m = nbs[0];
#pragma unroll
                for (int k = 1; k < NO_; ++k) m = fmaxf(m, nbs[k]);
                float ssum = 0.f;
#pragma unroll
                for (int k = 0; k < NO_; ++k) ssum += __expf(nbs[k] - m);
                cmat[i * NO_ + tid] = __expf(nbs[tid] - m) / ssum;
            }
            __syncthreads();
        }
        gsync(base + 3, flags);
    }
}

// ===================== fallback path (proven R4 kernels, small ws) =====================

__global__ __launch_bounds__(256) void c_old(float* __restrict__ blog,
                                             float* __restrict__ cmat, int init)
{
    int i = blockIdx.x * 256 + threadIdx.x;
    if (i >= NI_) return;
    if (init) {
#pragma unroll
        for (int j = 0; j < NO_; ++j) { cmat[i * NO_ + j] = 0.1f; blog[i * NO_ + j] = 0.f; }
        return;
    }
    float r[NO_]; float m = -1e30f;
#pragma unroll
    for (int j = 0; j < NO_; ++j) { r[j] = blog[i * NO_ + j]; m = fmaxf(m, r[j]); }
    float s = 0.f;
#pragma unroll
    for (int j = 0; j < NO_; ++j) { r[j] = __expf(r[j] - m); s += r[j]; }
    float inv = 1.f / s;
#pragma unroll
    for (int j = 0; j < NO_; ++j) cmat[i * NO_ + j] = r[j] * inv;
}

__global__ __launch_bounds__(640) void sv_old(const float* __restrict__ x,
                                              const float* __restrict__ W,
                                              const float* __restrict__ cmat,
                                              float* __restrict__ vbuf,
                                              float* __restrict__ out, int write_out)
{
    __shared__ __align__(16) float xL[NI_ * DI_];
    __shared__ float sred[4 * PAIRS_];
    __shared__ float sfin[PAIRS_];
    int b = blockIdx.x;
    {
        const float4* xs = (const float4*)(x + (size_t)b * NI_ * DI_);
        for (int t = threadIdx.x; t < NI_ * DI_ / 4; t += 640) {
            float4 v4 = xs[t];
            int f = 4 * t; int d = f / NI_; int i = f - d * NI_;
            xL[i * DI_ + d] = v4.x; xL[(i+1) * DI_ + d] = v4.y;
            xL[(i+2) * DI_ + d] = v4.z; xL[(i+3) * DI_ + d] = v4.w;
        }
    }
    __syncthreads();
    int pair = threadIdx.x % PAIRS_;
    int seg  = threadIdx.x / PAIRS_;
    int j    = pair >> 4;
    const float4* Wq = (const float4*)W;
    float acc = 0.f;
    int i0 = seg * (NI_ / 4);
    for (int i = i0; i < i0 + NI_ / 4; ++i) {
        float4 w0 = Wq[(i * PAIRS_ + pair) * 2];
        float4 w1 = Wq[(i * PAIRS_ + pair) * 2 + 1];
        const float* xp = &xL[i * DI_];
        float u = w0.x * xp[0] + w0.y * xp[1] + w0.z * xp[2] + w0.w * xp[3]
                + w1.x * xp[4] + w1.y * xp[5] + w1.z * xp[6] + w1.w * xp[7];
        acc = fmaf(cmat[i * NO_ + j], u, acc);
    }
    sred[threadIdx.x] = acc;
    __syncthreads();
    float s = 0.f;
    if (threadIdx.x < PAIRS_) {
        s = sred[threadIdx.x] + sred[PAIRS_ + threadIdx.x]
          + sred[2 * PAIRS_ + threadIdx.x] + sred[3 * PAIRS_ + threadIdx.x];
        sfin[threadIdx.x] = s;
    }
    __syncthreads();
    if (threadIdx.x < PAIRS_) {
        int jj = threadIdx.x >> 4;
        float sq = 0.f;
#pragma unroll
        for (int o = 0; o < DO_; ++o) { float t = sfin[(jj << 4) + o]; sq = fmaf(t, t, sq); }
        float vv = s * (sq / (1.f + sq)) * rsqrtf(sq + 1e-9f);
        vbuf[b * PAIRS_ + threadIdx.x] = vv;
        if (write_out) out[b * PAIRS_ + threadIdx.x] = vv;
    }
}

__global__ __launch_bounds__(256) void agree_old(const float* __restrict__ x,
                                                 const float* __restrict__ W,
                                                 const float* __restrict__ vbuf,
                                                 float* __restrict__ blog)
{
    int i = blockIdx.x;
    int b = threadIdx.x;
    float xr[DI_];
#pragma unroll
    for (int d = 0; d < DI_; ++d) xr[d] = x[((size_t)b * DI_ + d) * NI_ + i];
    __shared__ float red[4][NO_];
    int lane = threadIdx.x & 63;
    int wv   = threadIdx.x >> 6;
    for (int j = 0; j < NO_; ++j) {
        const float* vp = &vbuf[b * PAIRS_ + j * DO_];
        float aj = 0.f;
#pragma unroll
        for (int o = 0; o < DO_; ++o) {
            const float* wr = W + (size_t)((i * NO_ + j) * DO_ + o) * DI_;
            float u = wr[0] * xr[0] + wr[1] * xr[1] + wr[2] * xr[2] + wr[3] * xr[3]
                    + wr[4] * xr[4] + wr[5] * xr[5] + wr[6] * xr[6] + wr[7] * xr[7];
            aj = fmaf(u, vp[o], aj);
        }
        float val = aj;
        for (int off = 32; off > 0; off >>= 1) val += __shfl_down(val, off);
        if (lane == 0) red[wv][j] = val;
    }
    __syncthreads();
    if (threadIdx.x < NO_) {
        float sum = red[0][threadIdx.x] + red[1][threadIdx.x]
                  + red[2][threadIdx.x] + red[3][threadIdx.x];
        blog[i * NO_ + threadIdx.x] += sum * (1.f / B_);
    }
}

// ===================== launch =====================

extern "C" void kernel_launch(void* const* d_in, const int* in_sizes, int n_in,
                              void* d_out, int out_size, void* d_ws, size_t ws_size,
                              hipStream_t stream)
{
    const float* x = (const float*)d_in[0];   // [256,8,1152]
    const float* W = (const float*)d_in[1];   // [1152,10,16,8]
    float* out = (float*)d_out;               // [256,10,16]

    const size_t XT_N  = (size_t)NI_ * DI_ * B_;           // 2,359,296
    const size_t LOG_N = NI_ * NO_;                        // 11,520
    const size_t V_N   = PAIRS_ * B_;                      // 40,960
    const size_t P_N   = (size_t)SEGS_ * PAIRS_ * B_;      // 3,932,160
    const size_t P2_N  = (size_t)SC_ * PAIRS_ * B_;        // 163,840
    const size_t FLB   = (size_t)NSYNC_ * NBLK_ * sizeof(int);   // 42,240 B
    const size_t NEED  = (XT_N + 2 * LOG_N + V_N + P_N + P2_N) * sizeof(float) + FLB + 64;

    if (ws_size >= NEED) {
        float* xT      = (float*)d_ws;
        float* blog    = xT + XT_N;
        float* cmat    = blog + LOG_N;
        float* vbuf    = cmat + LOG_N;
        float* partial = vbuf + V_N;
        float* part2   = partial + P_N;
        int*   flags   = (int*)(part2 + P2_N);
        caps_kernel<<<NBLK_, 256, 0, stream>>>(x, W, xT, blog, cmat, vbuf,
                                               partial, part2, flags, out);
    } else {
        float* blog = (float*)d_ws;
        float* cmat = blog + LOG_N;
        float* vbuf = cmat + LOG_N;
        for (int it = 0; it < 3; ++it) {
            c_old<<<(NI_ + 255) / 256, 256, 0, stream>>>(blog, cmat, it == 0 ? 1 : 0);
            sv_old<<<B_, 640, 0, stream>>>(x, W, cmat, vbuf, out, it == 2 ? 1 : 0);
            if (it < 2) agree_old<<<NI_, 256, 0, stream>>>(x, W, vbuf, blog);
        }
    }
}

// Round 9
// 184.922 us; speedup vs baseline: 17.9554x; 17.9554x over previous
//
#include <hip/hip_runtime.h>

#define B_     256
#define NI_    1152
#define NO_    10
#define DO_    16
#define DI_    8
#define PAIRS_ 160
#define SEGS_  128
#define ISEG_  (NI_/SEGS_)  // 9
#define PP_    5            // pairs per wave (8 ps x 4 waves x 5 = 160)

// ===================== fast path =====================

// Tiled transpose x[b,d,i] -> xT[(i*8+d)*256+b]; blocks 576.. init blog/cmat.
__global__ __launch_bounds__(256) void prep_kernel(const float* __restrict__ x,
                                                   float* __restrict__ xT,
                                                   float* __restrict__ blog,
                                                   float* __restrict__ cmat)
{
    int vb = blockIdx.x;
    int tid = threadIdx.x, lane = tid & 63, wv = tid >> 6;
    if (vb < 576) {                         // (d, b-tile, i-tile): 8 x 4 x 18
        __shared__ float tile[64 * 65];
        int d = vb & 7, rest = vb >> 3, tb = rest & 3, ti = rest >> 2;
        int i0 = ti * 64, b0 = tb * 64;
#pragma unroll
        for (int k = 0; k < 16; ++k) {      // read: lanes over i (coalesced)
            int bL = wv * 16 + k;
            tile[bL * 65 + lane] = x[(size_t)(b0 + bL) * (NI_ * DI_) + d * NI_ + i0 + lane];
        }
        __syncthreads();
#pragma unroll
        for (int k = 0; k < 16; ++k) {      // write: lanes over b (coalesced)
            int iL = wv * 16 + k;
            xT[((size_t)(i0 + iL) * DI_ + d) * B_ + b0 + lane] = tile[lane * 65 + iL];
        }
    } else {
        int g = (vb - 576) * 256 + tid;     // 45 blocks cover 11520
        if (g < NI_ * NO_) { blog[g] = 0.f; cmat[g] = 0.1f; }
    }
}

// Block = (ps 0..7, seg 0..127); 4 waves, no LDS, no barriers.
// Lanes hold b = 4*lane..+3 (float4 x loads straight from L2, register-prefetched).
// W/cmat addresses wave-uniform -> s_load.
__global__ __launch_bounds__(256, 4) void sv_kernel(const float* __restrict__ xT,
                                                    const float* __restrict__ W,
                                                    const float* __restrict__ cmat,
                                                    float* __restrict__ partial)
{
    int ps   = blockIdx.x;
    int seg  = blockIdx.y;
    int tid  = threadIdx.x;
    int lane = tid & 63;
    int wv   = __builtin_amdgcn_readfirstlane(tid >> 6);
    int p0   = ps * (4 * PP_) + wv * PP_;
    int b0   = lane * 4;
    int i0   = seg * ISEG_;

    float acc[PP_][4];
#pragma unroll
    for (int p = 0; p < PP_; ++p)
#pragma unroll
        for (int r = 0; r < 4; ++r) acc[p][r] = 0.f;

    float4 nx[DI_];
#pragma unroll
    for (int d = 0; d < DI_; ++d)
        nx[d] = *(const float4*)&xT[((size_t)i0 * DI_ + d) * B_ + b0];

    for (int ii = 0; ii < ISEG_; ++ii) {
        int i = i0 + ii;
        float4 cx[DI_];
#pragma unroll
        for (int d = 0; d < DI_; ++d) cx[d] = nx[d];
        if (ii + 1 < ISEG_) {
#pragma unroll
            for (int d = 0; d < DI_; ++d)           // prefetch next i while computing
                nx[d] = *(const float4*)&xT[((size_t)(i + 1) * DI_ + d) * B_ + b0];
        }
        const float* __restrict__ crow = cmat + i * NO_;                      // uniform
        const float* __restrict__ wb   = W + (size_t)(i * PAIRS_ + p0) * DI_; // uniform
#pragma unroll
        for (int p = 0; p < PP_; ++p) {
            const float* wr = wb + p * DI_;                                   // s_load x8
            float cv = crow[(p0 + p) >> 4];
            float u0 = wr[0] * cx[0].x, u1 = wr[0] * cx[0].y;
            float u2 = wr[0] * cx[0].z, u3 = wr[0] * cx[0].w;
#pragma unroll
            for (int d = 1; d < DI_; ++d) {
                u0 = fmaf(wr[d], (&cx[d].x)[0], u0);
                u1 = fmaf(wr[d], (&cx[d].x)[1], u1);
                u2 = fmaf(wr[d], (&cx[d].x)[2], u2);
                u3 = fmaf(wr[d], (&cx[d].x)[3], u3);
            }
            acc[p][0] = fmaf(cv, u0, acc[p][0]);
            acc[p][1] = fmaf(cv, u1, acc[p][1]);
            acc[p][2] = fmaf(cv, u2, acc[p][2]);
            acc[p][3] = fmaf(cv, u3, acc[p][3]);
        }
    }
#pragma unroll
    for (int p = 0; p < PP_; ++p)
        *(float4*)&partial[(size_t)(seg * PAIRS_ + p0 + p) * B_ + b0] =
            make_float4(acc[p][0], acc[p][1], acc[p][2], acc[p][3]);
}

// Fused reduce+squash: grid (10 j, 16 b-chunks); thread = (o, b_l 16).
// Sums 128 segs, squashes over o, writes vbuf[pair][b] (+ out on last iter).
__global__ __launch_bounds__(256) void red_kernel(const float* __restrict__ partial,
                                                  float* __restrict__ vbuf,
                                                  float* __restrict__ out,
                                                  int write_out)
{
    int j   = blockIdx.x;
    int bc  = blockIdx.y;
    int o   = threadIdx.x >> 4;
    int b_l = threadIdx.x & 15;
    int b   = bc * 16 + b_l;
    int pair = j * DO_ + o;

    float s = 0.f;
    for (int seg = 0; seg < SEGS_; ++seg)
        s += partial[(size_t)(seg * PAIRS_ + pair) * B_ + b];

    __shared__ float so[DO_][17];
    so[o][b_l] = s;
    __syncthreads();
    float sq = 0.f;
#pragma unroll
    for (int oo = 0; oo < DO_; ++oo) { float t = so[oo][b_l]; sq = fmaf(t, t, sq); }
    float f = (sq / (1.f + sq)) * rsqrtf(sq + 1e-9f);
    float vv = s * f;
    vbuf[pair * B_ + b] = vv;
    if (write_out) out[(size_t)b * PAIRS_ + pair] = vv;
}

// Block per i; agreement update AND next-iter softmax fused (R7-proven).
__global__ __launch_bounds__(256) void agree_kernel(const float* __restrict__ xT,
                                                    const float* __restrict__ W,
                                                    const float* __restrict__ vbuf,
                                                    float* __restrict__ blog,
                                                    float* __restrict__ cmat)
{
    int i    = blockIdx.x;
    int lane = threadIdx.x & 63;
    int wv   = __builtin_amdgcn_readfirstlane(threadIdx.x >> 6);
    int b0   = lane * 4;

    float xv[DI_][4];
#pragma unroll
    for (int d = 0; d < DI_; ++d) {
        float4 t4 = *(const float4*)&xT[((size_t)i * DI_ + d) * B_ + b0];
        xv[d][0] = t4.x; xv[d][1] = t4.y; xv[d][2] = t4.z; xv[d][3] = t4.w;
    }
    __shared__ float js[NO_];
    __shared__ float nbs[NO_];
    for (int j = wv; j < NO_; j += 4) {
        const float* __restrict__ wj = W + (size_t)(i * NO_ + j) * DO_ * DI_;
        float aj = 0.f;
#pragma unroll
        for (int o = 0; o < DO_; ++o) {
            const float* wr = wj + o * DI_;                              // s_load x8
            float4 vv4 = *(const float4*)&vbuf[(j * DO_ + o) * B_ + b0]; // coalesced
            float u0 = wr[0] * xv[0][0], u1 = wr[0] * xv[0][1];
            float u2 = wr[0] * xv[0][2], u3 = wr[0] * xv[0][3];
#pragma unroll
            for (int d = 1; d < DI_; ++d) {
                u0 = fmaf(wr[d], xv[d][0], u0); u1 = fmaf(wr[d], xv[d][1], u1);
                u2 = fmaf(wr[d], xv[d][2], u2); u3 = fmaf(wr[d], xv[d][3], u3);
            }
            aj = fmaf(u0, vv4.x, aj); aj = fmaf(u1, vv4.y, aj);
            aj = fmaf(u2, vv4.z, aj); aj = fmaf(u3, vv4.w, aj);
        }
        for (int off = 32; off > 0; off >>= 1) aj += __shfl_down(aj, off);
        if (lane == 0) js[j] = aj;
    }
    __syncthreads();
    if (threadIdx.x < NO_) {
        float nb = blog[i * NO_ + threadIdx.x] + js[threadIdx.x] * (1.f / B_);
        blog[i * NO_ + threadIdx.x] = nb;
        nbs[threadIdx.x] = nb;
    }
    __syncthreads();
    if (threadIdx.x < NO_) {
        float m = nbs[0];
#pragma unroll
        for (int k = 1; k < NO_; ++k) m = fmaxf(m, nbs[k]);
        float ssum = 0.f;
#pragma unroll
        for (int k = 0; k < NO_; ++k) ssum += __expf(nbs[k] - m);
        cmat[i * NO_ + threadIdx.x] = __expf(nbs[threadIdx.x] - m) / ssum;
    }
}

// ===================== fallback path (proven R4 kernels, small ws) =====================

__global__ __launch_bounds__(256) void c_old(float* __restrict__ blog,
                                             float* __restrict__ cmat, int init)
{
    int i = blockIdx.x * 256 + threadIdx.x;
    if (i >= NI_) return;
    if (init) {
#pragma unroll
        for (int j = 0; j < NO_; ++j) { cmat[i * NO_ + j] = 0.1f; blog[i * NO_ + j] = 0.f; }
        return;
    }
    float r[NO_]; float m = -1e30f;
#pragma unroll
    for (int j = 0; j < NO_; ++j) { r[j] = blog[i * NO_ + j]; m = fmaxf(m, r[j]); }
    float s = 0.f;
#pragma unroll
    for (int j = 0; j < NO_; ++j) { r[j] = __expf(r[j] - m); s += r[j]; }
    float inv = 1.f / s;
#pragma unroll
    for (int j = 0; j < NO_; ++j) cmat[i * NO_ + j] = r[j] * inv;
}

__global__ __launch_bounds__(640) void sv_old(const float* __restrict__ x,
                                              const float* __restrict__ W,
                                              const float* __restrict__ cmat,
                                              float* __restrict__ vbuf,
                                              float* __restrict__ out, int write_out)
{
    __shared__ __align__(16) float xL[NI_ * DI_];
    __shared__ float sred[4 * PAIRS_];
    __shared__ float sfin[PAIRS_];
    int b = blockIdx.x;
    {
        const float4* xs = (const float4*)(x + (size_t)b * NI_ * DI_);
        for (int t = threadIdx.x; t < NI_ * DI_ / 4; t += 640) {
            float4 v4 = xs[t];
            int f = 4 * t; int d = f / NI_; int i = f - d * NI_;
            xL[i * DI_ + d] = v4.x; xL[(i+1) * DI_ + d] = v4.y;
            xL[(i+2) * DI_ + d] = v4.z; xL[(i+3) * DI_ + d] = v4.w;
        }
    }
    __syncthreads();
    int pair = threadIdx.x % PAIRS_;
    int seg  = threadIdx.x / PAIRS_;
    int j    = pair >> 4;
    const float4* Wq = (const float4*)W;
    float acc = 0.f;
    int i0 = seg * (NI_ / 4);
    for (int i = i0; i < i0 + NI_ / 4; ++i) {
        float4 w0 = Wq[(i * PAIRS_ + pair) * 2];
        float4 w1 = Wq[(i * PAIRS_ + pair) * 2 + 1];
        const float* xp = &xL[i * DI_];
        float u = w0.x * xp[0] + w0.y * xp[1] + w0.z * xp[2] + w0.w * xp[3]
                + w1.x * xp[4] + w1.y * xp[5] + w1.z * xp[6] + w1.w * xp[7];
        acc = fmaf(cmat[i * NO_ + j], u, acc);
    }
    sred[threadIdx.x] = acc;
    __syncthreads();
    float s = 0.f;
    if (threadIdx.x < PAIRS_) {
        s = sred[threadIdx.x] + sred[PAIRS_ + threadIdx.x]
          + sred[2 * PAIRS_ + threadIdx.x] + sred[3 * PAIRS_ + threadIdx.x];
        sfin[threadIdx.x] = s;
    }
    __syncthreads();
    if (threadIdx.x < PAIRS_) {
        int jj = threadIdx.x >> 4;
        float sq = 0.f;
#pragma unroll
        for (int o = 0; o < DO_; ++o) { float t = sfin[(jj << 4) + o]; sq = fmaf(t, t, sq); }
        float vv = s * (sq / (1.f + sq)) * rsqrtf(sq + 1e-9f);
        vbuf[b * PAIRS_ + threadIdx.x] = vv;
        if (write_out) out[b * PAIRS_ + threadIdx.x] = vv;
    }
}

__global__ __launch_bounds__(256) void agree_old(const float* __restrict__ x,
                                                 const float* __restrict__ W,
                                                 const float* __restrict__ vbuf,
                                                 float* __restrict__ blog)
{
    int i = blockIdx.x;
    int b = threadIdx.x;
    float xr[DI_];
#pragma unroll
    for (int d = 0; d < DI_; ++d) xr[d] = x[((size_t)b * DI_ + d) * NI_ + i];
    __shared__ float red[4][NO_];
    int lane = threadIdx.x & 63;
    int wv   = threadIdx.x >> 6;
    for (int j = 0; j < NO_; ++j) {
        const float* vp = &vbuf[b * PAIRS_ + j * DO_];
        float aj = 0.f;
#pragma unroll
        for (int o = 0; o < DO_; ++o) {
            const float* wr = W + (size_t)((i * NO_ + j) * DO_ + o) * DI_;
            float u = wr[0] * xr[0] + wr[1] * xr[1] + wr[2] * xr[2] + wr[3] * xr[3]
                    + wr[4] * xr[4] + wr[5] * xr[5] + wr[6] * xr[6] + wr[7] * xr[7];
            aj = fmaf(u, vp[o], aj);
        }
        float val = aj;
        for (int off = 32; off > 0; off >>= 1) val += __shfl_down(val, off);
        if (lane == 0) red[wv][j] = val;
    }
    __syncthreads();
    if (threadIdx.x < NO_) {
        float sum = red[0][threadIdx.x] + red[1][threadIdx.x]
                  + red[2][threadIdx.x] + red[3][threadIdx.x];
        blog[i * NO_ + threadIdx.x] += sum * (1.f / B_);
    }
}

// ===================== launch =====================

extern "C" void kernel_launch(void* const* d_in, const int* in_sizes, int n_in,
                              void* d_out, int out_size, void* d_ws, size_t ws_size,
                              hipStream_t stream)
{
    const float* x = (const float*)d_in[0];   // [256,8,1152]
    const float* W = (const float*)d_in[1];   // [1152,10,16,8]
    float* out = (float*)d_out;               // [256,10,16]

    const size_t XT_N  = (size_t)NI_ * DI_ * B_;         // 2,359,296
    const size_t LOG_N = NI_ * NO_;                      // 11,520
    const size_t V_N   = PAIRS_ * B_;                    // 40,960
    const size_t P_N   = (size_t)SEGS_ * PAIRS_ * B_;    // 5,242,880
    const size_t NEED  = (XT_N + 2 * LOG_N + V_N + P_N) * sizeof(float);  // ~30.7 MB

    if (ws_size >= NEED) {
        float* xT      = (float*)d_ws;
        float* blog    = xT + XT_N;
        float* cmat    = blog + LOG_N;
        float* vbuf    = cmat + LOG_N;
        float* partial = vbuf + V_N;

        prep_kernel<<<576 + 45, 256, 0, stream>>>(x, xT, blog, cmat);
        for (int it = 0; it < 3; ++it) {
            sv_kernel<<<dim3(8, SEGS_), 256, 0, stream>>>(xT, W, cmat, partial);
            red_kernel<<<dim3(NO_, B_ / 16), 256, 0, stream>>>(partial, vbuf, out,
                                                               it == 2 ? 1 : 0);
            if (it < 2) agree_kernel<<<NI_, 256, 0, stream>>>(xT, W, vbuf, blog, cmat);
        }
    } else {
        float* blog = (float*)d_ws;
        float* cmat = blog + LOG_N;
        float* vbuf = cmat + LOG_N;
        for (int it = 0; it < 3; ++it) {
            c_old<<<(NI_ + 255) / 256, 256, 0, stream>>>(blog, cmat, it == 0 ? 1 : 0);
            sv_old<<<B_, 640, 0, stream>>>(x, W, cmat, vbuf, out, it == 2 ? 1 : 0);
            if (it < 2) agree_old<<<NI_, 256, 0, stream>>>(x, W, vbuf, blog);
        }
    }
}